// Round 1
// baseline (579.399 us; speedup 1.0000x reference)
//
#include <hip/hip_runtime.h>
#include <math.h>

#define NEG_SLOPE 0.2f
#define CAP 256   // max degree on the fast LDS path; fallback handles larger

__device__ __forceinline__ float wred_sum(float v) {
#pragma unroll
    for (int o = 32; o >= 1; o >>= 1) v += __shfl_xor(v, o, 64);
    return v;
}
__device__ __forceinline__ float wred_max(float v) {
#pragma unroll
    for (int o = 32; o >= 1; o >>= 1) v = fmaxf(v, __shfl_xor(v, o, 64));
    return v;
}

// ---------------- CSR build ----------------

__global__ __launch_bounds__(256) void k_init(int* deg, int* fill, int N) {
    int i = blockIdx.x * 256 + threadIdx.x;
    if (i < N) { deg[i] = 1; fill[i] = 0; }   // deg starts at 1: self-loop
}

__global__ __launch_bounds__(256) void k_count(const int* __restrict__ dst, int* deg, int E) {
    int i = blockIdx.x * 256 + threadIdx.x;
    if (i < E) atomicAdd(&deg[dst[i]], 1);
}

// block scans 1024 elements (256 threads x 4)
__global__ __launch_bounds__(256) void k_scan1(const int* __restrict__ deg, int* __restrict__ rowptr,
                                               int* __restrict__ bsums, int N) {
    __shared__ int sdata[256];
    int base = blockIdx.x * 1024;
    int idx0 = base + threadIdx.x * 4;
    int v0 = (idx0 + 0 < N) ? deg[idx0 + 0] : 0;
    int v1 = (idx0 + 1 < N) ? deg[idx0 + 1] : 0;
    int v2 = (idx0 + 2 < N) ? deg[idx0 + 2] : 0;
    int v3 = (idx0 + 3 < N) ? deg[idx0 + 3] : 0;
    int s = v0 + v1 + v2 + v3;
    sdata[threadIdx.x] = s;
    __syncthreads();
#pragma unroll
    for (int off = 1; off < 256; off <<= 1) {
        int t = (threadIdx.x >= off) ? sdata[threadIdx.x - off] : 0;
        __syncthreads();
        sdata[threadIdx.x] += t;
        __syncthreads();
    }
    int excl = sdata[threadIdx.x] - s;
    if (threadIdx.x == 255) bsums[blockIdx.x] = sdata[255];
    int run = excl;
    if (idx0 + 0 < N) rowptr[idx0 + 0] = run; run += v0;
    if (idx0 + 1 < N) rowptr[idx0 + 1] = run; run += v1;
    if (idx0 + 2 < N) rowptr[idx0 + 2] = run; run += v2;
    if (idx0 + 3 < N) rowptr[idx0 + 3] = run;
}

__global__ __launch_bounds__(1024) void k_scan2(int* __restrict__ bsums, int nb,
                                                int* __restrict__ rowptr, int N, int total) {
    __shared__ int sdata[1024];
    int t = threadIdx.x;
    int v = (t < nb) ? bsums[t] : 0;
    sdata[t] = v;
    __syncthreads();
#pragma unroll
    for (int off = 1; off < 1024; off <<= 1) {
        int u = (t >= off) ? sdata[t - off] : 0;
        __syncthreads();
        sdata[t] += u;
        __syncthreads();
    }
    if (t < nb) bsums[t] = sdata[t] - v;   // exclusive
    if (t == 0) rowptr[N] = total;
}

__global__ __launch_bounds__(256) void k_scan3(int* __restrict__ rowptr, const int* __restrict__ bsums, int N) {
    int i = blockIdx.x * 256 + threadIdx.x;
    if (i < N) rowptr[i] += bsums[i >> 10];
}

__global__ __launch_bounds__(256) void k_fill(const int* __restrict__ src, const int* __restrict__ dst,
                                              const int* __restrict__ rowptr, int* fill,
                                              int* __restrict__ csr, int E, int N) {
    int i = blockIdx.x * 256 + threadIdx.x;
    if (i < E) {
        int d = dst[i];
        int pos = atomicAdd(&fill[d], 1);
        csr[rowptr[d] + pos] = src[i];
    } else if (i < E + N) {
        int n = i - E;                      // self-loop
        int pos = atomicAdd(&fill[n], 1);
        csr[rowptr[n] + pos] = n;
    }
}

// ---------------- GEMM: H = X @ W (+bias), optionally ss = H a_s, sd = H a_d ----------------
// block = 256 = 4 waves; each wave computes 4 node rows; lane = output dim.
// W staged in LDS; x rows read via wave-uniform (scalar) loads.

template <int K, int OUT, bool SS, bool BIAS>
__global__ __launch_bounds__(256) void k_gemm(const float* __restrict__ X, const float* __restrict__ W,
                                              const float* __restrict__ a_s, const float* __restrict__ a_d,
                                              const float* __restrict__ bias,
                                              float* __restrict__ H, float* __restrict__ ss,
                                              float* __restrict__ sd, int N) {
    __shared__ float wl[K * OUT];
    for (int i = threadIdx.x; i < K * OUT; i += 256) wl[i] = W[i];
    __syncthreads();

    int w = __builtin_amdgcn_readfirstlane((int)(threadIdx.x >> 6));
    int lane = (int)(threadIdx.x & 63);
    int kk = (OUT < 64) ? ((lane < OUT) ? lane : (OUT - 1)) : lane;

    int nb = blockIdx.x * 16 + w * 4;
    int n0 = nb, n1 = nb + 1, n2 = nb + 2, n3 = nb + 3;
    bool p0 = n0 < N, p1 = n1 < N, p2 = n2 < N, p3 = n3 < N;
    int c0 = p0 ? n0 : N - 1, c1 = p1 ? n1 : N - 1, c2 = p2 ? n2 : N - 1, c3 = p3 ? n3 : N - 1;
    const float* x0 = X + (size_t)c0 * K;
    const float* x1 = X + (size_t)c1 * K;
    const float* x2 = X + (size_t)c2 * K;
    const float* x3 = X + (size_t)c3 * K;

    float acc0 = 0.f, acc1 = 0.f, acc2 = 0.f, acc3 = 0.f;
#pragma unroll 8
    for (int i = 0; i < K; ++i) {
        float wv = wl[i * OUT + kk];
        acc0 = fmaf(x0[i], wv, acc0);
        acc1 = fmaf(x1[i], wv, acc1);
        acc2 = fmaf(x2[i], wv, acc2);
        acc3 = fmaf(x3[i], wv, acc3);
    }

    if (SS) {
        float asv = a_s[kk], adv = a_d[kk];
        float s0 = wred_sum(acc0 * asv), d0 = wred_sum(acc0 * adv);
        float s1 = wred_sum(acc1 * asv), d1 = wred_sum(acc1 * adv);
        float s2 = wred_sum(acc2 * asv), d2 = wred_sum(acc2 * adv);
        float s3 = wred_sum(acc3 * asv), d3 = wred_sum(acc3 * adv);
        if (lane == 0) {
            if (p0) { ss[n0] = s0; sd[n0] = d0; }
            if (p1) { ss[n1] = s1; sd[n1] = d1; }
            if (p2) { ss[n2] = s2; sd[n2] = d2; }
            if (p3) { ss[n3] = s3; sd[n3] = d3; }
        }
    }

    float bv = 0.f;
    if (BIAS) bv = bias[kk];
    if (lane < OUT) {
        if (p0) H[(size_t)n0 * OUT + lane] = acc0 + bv;
        if (p1) H[(size_t)n1 * OUT + lane] = acc1 + bv;
        if (p2) H[(size_t)n2 * OUT + lane] = acc2 + bv;
        if (p3) H[(size_t)n3 * OUT + lane] = acc3 + bv;
    }
}

// ---------------- Aggregation: z[n] = elu( sum_j alpha_j h[src_j] + b ) ----------------
// one wave per dst node; lane = feature dim (HID=64).

__global__ __launch_bounds__(256) void k_agg(const int* __restrict__ rowptr, const int* __restrict__ csr,
                                             const float* __restrict__ ss, const float* __restrict__ sd,
                                             const float* __restrict__ h, const float* __restrict__ bias,
                                             float* __restrict__ z, int N) {
    __shared__ float2 ps[4 * CAP];
    int w = __builtin_amdgcn_readfirstlane((int)(threadIdx.x >> 6));
    int lane = (int)(threadIdx.x & 63);
    int n = blockIdx.x * 4 + w;
    if (n >= N) return;

    int ro = rowptr[n];
    int deg = rowptr[n + 1] - ro;
    float sdn = sd[n];
    float bv = bias[lane];
    float2* myps = ps + w * CAP;

    float acc = 0.f;
    float inv;

    if (deg <= CAP) {
        float m = -1e30f;
        for (int j = lane; j < deg; j += 64) {
            int s = csr[ro + j];
            float e = ss[s] + sdn;
            e = (e >= 0.f) ? e : NEG_SLOPE * e;
            myps[j] = make_float2(e, __int_as_float(s));
            m = fmaxf(m, e);
        }
        m = wred_max(m);
        float sum = 0.f;
        for (int j = lane; j < deg; j += 64) {
            float p = expf(myps[j].x - m);
            myps[j].x = p;
            sum += p;
        }
        sum = wred_sum(sum);
        inv = 1.f / (sum + 1e-16f);
        for (int j = 0; j < deg; ++j) {
            float2 a = myps[j];                           // broadcast ds_read_b64
            int s = __float_as_int(a.y);
            acc = fmaf(a.x, h[(size_t)s * 64 + lane], acc);
        }
    } else {
        // recompute fallback (deg > CAP): statistically never taken, correctness-guarded
        float m = -1e30f;
        for (int j = lane; j < deg; j += 64) {
            int s = csr[ro + j];
            float e = ss[s] + sdn;
            e = (e >= 0.f) ? e : NEG_SLOPE * e;
            m = fmaxf(m, e);
        }
        m = wred_max(m);
        float sum = 0.f;
        for (int j = lane; j < deg; j += 64) {
            int s = csr[ro + j];
            float e = ss[s] + sdn;
            e = (e >= 0.f) ? e : NEG_SLOPE * e;
            sum += expf(e - m);
        }
        sum = wred_sum(sum);
        inv = 1.f / (sum + 1e-16f);
        for (int j = 0; j < deg; ++j) {
            int s = csr[ro + j];
            float e = ss[s] + sdn;
            e = (e >= 0.f) ? e : NEG_SLOPE * e;
            float p = expf(e - m);
            acc = fmaf(p, h[(size_t)s * 64 + lane], acc);
        }
    }

    float o = acc * inv + bv;
    z[(size_t)n * 64 + lane] = (o > 0.f) ? o : expm1f(o);
}

// ---------------- launch ----------------

extern "C" void kernel_launch(void* const* d_in, const int* in_sizes, int n_in,
                              void* d_out, int out_size, void* d_ws, size_t ws_size,
                              hipStream_t stream) {
    const float* x   = (const float*)d_in[0];
    const int*   ei  = (const int*)d_in[1];
    const float* W0  = (const float*)d_in[2];
    const float* as0 = (const float*)d_in[3];
    const float* ad0 = (const float*)d_in[4];
    const float* b0  = (const float*)d_in[5];
    const float* W1  = (const float*)d_in[6];
    const float* as1 = (const float*)d_in[7];
    const float* ad1 = (const float*)d_in[8];
    const float* b1  = (const float*)d_in[9];
    const float* Wl  = (const float*)d_in[10];
    const float* bl  = (const float*)d_in[11];
    float* out = (float*)d_out;

    int N = in_sizes[0] / 128;
    int E = in_sizes[1] / 2;
    const int* srcp = ei;
    const int* dstp = ei + E;

    char* wp = (char*)d_ws;
    auto alloc = [&](size_t bytes) { void* p = (void*)wp; wp += (bytes + 255) & ~(size_t)255; return p; };
    float* h      = (float*)alloc((size_t)N * 64 * 4);
    float* z      = (float*)alloc((size_t)N * 64 * 4);
    float* ssb    = (float*)alloc((size_t)N * 4);
    float* sdb    = (float*)alloc((size_t)N * 4);
    int*   deg    = (int*)alloc((size_t)N * 4);
    int*   fill   = (int*)alloc((size_t)N * 4);
    int*   rowptr = (int*)alloc((size_t)(N + 1) * 4);
    int*   bsums  = (int*)alloc(1024 * 4);
    int*   csr    = (int*)alloc((size_t)(E + N) * 4);

    int nb = (N + 1023) / 1024;

    k_init<<<(N + 255) / 256, 256, 0, stream>>>(deg, fill, N);
    k_count<<<(E + 255) / 256, 256, 0, stream>>>(dstp, deg, E);
    k_scan1<<<nb, 256, 0, stream>>>(deg, rowptr, bsums, N);
    k_scan2<<<1, 1024, 0, stream>>>(bsums, nb, rowptr, N, E + N);
    k_scan3<<<(N + 255) / 256, 256, 0, stream>>>(rowptr, bsums, N);
    k_fill<<<(E + N + 255) / 256, 256, 0, stream>>>(srcp, dstp, rowptr, fill, csr, E, N);

    // layer 0: h = x @ W0 ; ss/sd ; aggregate+elu -> z
    k_gemm<128, 64, true, false><<<(N + 15) / 16, 256, 0, stream>>>(x, W0, as0, ad0, nullptr, h, ssb, sdb, N);
    k_agg<<<(N + 3) / 4, 256, 0, stream>>>(rowptr, csr, ssb, sdb, h, b0, z, N);

    // layer 1: h = z @ W1 ; ss/sd ; aggregate+elu -> z (h reused)
    k_gemm<64, 64, true, false><<<(N + 15) / 16, 256, 0, stream>>>(z, W1, as1, ad1, nullptr, h, ssb, sdb, N);
    k_agg<<<(N + 3) / 4, 256, 0, stream>>>(rowptr, csr, ssb, sdb, h, b1, z, N);

    // classifier: out = z @ Wl + bl
    k_gemm<64, 40, false, true><<<(N + 15) / 16, 256, 0, stream>>>(z, Wl, nullptr, nullptr, bl, out, nullptr, nullptr, N);
}

// Round 2
// 537.273 us; speedup vs baseline: 1.0784x; 1.0784x over previous
//
#include <hip/hip_runtime.h>
#include <math.h>

#define NEG_SLOPE 0.2f
#define CAP 256   // max degree on the fast LDS path; fallback handles larger

__device__ __forceinline__ float wred_sum(float v) {
#pragma unroll
    for (int o = 32; o >= 1; o >>= 1) v += __shfl_xor(v, o, 64);
    return v;
}
__device__ __forceinline__ float wred_max(float v) {
#pragma unroll
    for (int o = 32; o >= 1; o >>= 1) v = fmaxf(v, __shfl_xor(v, o, 64));
    return v;
}

// ---------------- CSR build ----------------

__global__ __launch_bounds__(256) void k_init(int* deg, int N) {
    int i = blockIdx.x * 256 + threadIdx.x;
    if (i < N) deg[i] = 1;   // deg starts at 1: self-loop
}

__global__ __launch_bounds__(256) void k_count(const int* __restrict__ dst, int* __restrict__ deg, int E) {
    int i = blockIdx.x * 1024 + threadIdx.x;
#pragma unroll
    for (int u = 0; u < 4; ++u) {
        int idx = i + u * 256;
        if (idx < E) atomicAdd(&deg[dst[idx]], 1);
    }
}

// block scans 1024 elements (256 threads x 4)
__global__ __launch_bounds__(256) void k_scan1(const int* __restrict__ deg, int* __restrict__ rowptr,
                                               int* __restrict__ bsums, int N) {
    __shared__ int sdata[256];
    int base = blockIdx.x * 1024;
    int idx0 = base + threadIdx.x * 4;
    int v0 = (idx0 + 0 < N) ? deg[idx0 + 0] : 0;
    int v1 = (idx0 + 1 < N) ? deg[idx0 + 1] : 0;
    int v2 = (idx0 + 2 < N) ? deg[idx0 + 2] : 0;
    int v3 = (idx0 + 3 < N) ? deg[idx0 + 3] : 0;
    int s = v0 + v1 + v2 + v3;
    sdata[threadIdx.x] = s;
    __syncthreads();
#pragma unroll
    for (int off = 1; off < 256; off <<= 1) {
        int t = (threadIdx.x >= off) ? sdata[threadIdx.x - off] : 0;
        __syncthreads();
        sdata[threadIdx.x] += t;
        __syncthreads();
    }
    int excl = sdata[threadIdx.x] - s;
    if (threadIdx.x == 255) bsums[blockIdx.x] = sdata[255];
    int run = excl;
    if (idx0 + 0 < N) rowptr[idx0 + 0] = run; run += v0;
    if (idx0 + 1 < N) rowptr[idx0 + 1] = run; run += v1;
    if (idx0 + 2 < N) rowptr[idx0 + 2] = run; run += v2;
    if (idx0 + 3 < N) rowptr[idx0 + 3] = run;
}

__global__ __launch_bounds__(1024) void k_scan2(int* __restrict__ bsums, int nb,
                                                int* __restrict__ rowptr, int N, int total) {
    __shared__ int sdata[1024];
    int t = threadIdx.x;
    int v = (t < nb) ? bsums[t] : 0;
    sdata[t] = v;
    __syncthreads();
#pragma unroll
    for (int off = 1; off < 1024; off <<= 1) {
        int u = (t >= off) ? sdata[t - off] : 0;
        __syncthreads();
        sdata[t] += u;
        __syncthreads();
    }
    if (t < nb) bsums[t] = sdata[t] - v;   // exclusive
    if (t == 0) rowptr[N] = total;
}

__global__ __launch_bounds__(256) void k_scan3(int* __restrict__ rowptr, const int* __restrict__ bsums,
                                               int* __restrict__ cursor, int N) {
    int i = blockIdx.x * 256 + threadIdx.x;
    if (i < N) {
        int v = rowptr[i] + bsums[i >> 10];
        rowptr[i] = v;
        cursor[i] = v;     // k_fill's atomic cursor starts at rowptr
    }
}

__global__ __launch_bounds__(256) void k_fill(const int* __restrict__ src, const int* __restrict__ dst,
                                              int* __restrict__ cursor, int* __restrict__ csr,
                                              int E, int N) {
    int i = blockIdx.x * 1024 + threadIdx.x;
#pragma unroll
    for (int u = 0; u < 4; ++u) {
        int idx = i + u * 256;
        if (idx < E) {
            int pos = atomicAdd(&cursor[dst[idx]], 1);
            csr[pos] = src[idx];
        } else if (idx < E + N) {
            int n = idx - E;                  // self-loop
            int pos = atomicAdd(&cursor[n], 1);
            csr[pos] = n;
        }
    }
}

// ---------------- GEMM: H = X @ W (+bias), optionally ss = H a_s, sd = H a_d ----
// block = 256 (4 waves), 128 rows/block. Lane tile: 4 rows x 8 cols (compute width
// fixed 64; W zero-padded for OUTW<64). X chunk staged transposed in LDS.

template <int K, int OUTW, bool SS>
__global__ __launch_bounds__(256) void k_gemm(const float* __restrict__ X,
                                              const float* __restrict__ W,
                                              const float* __restrict__ a_s,
                                              const float* __restrict__ a_d,
                                              const float* __restrict__ bias,
                                              float* __restrict__ H,
                                              float* __restrict__ ss,
                                              float* __restrict__ sd, int N) {
    constexpr int CH = 16;             // k-chunk
    constexpr int XS = 132;            // xs row stride in words (128 + 4 pad, 16B-aligned)
    __shared__ __align__(16) float ws[K * 64];
    __shared__ __align__(16) float xs[CH * XS];

    // stage W
    if (OUTW == 64) {
        for (int i = threadIdx.x * 4; i < K * 64; i += 1024)
            *(float4*)&ws[i] = *(const float4*)&W[i];
    } else {
        for (int i = threadIdx.x; i < K * 64; i += 256) {
            int k = i >> 6, o = i & 63;
            ws[i] = (o < OUTW) ? W[k * OUTW + o] : 0.f;
        }
    }

    const int lane = threadIdx.x & 63;
    const int w    = threadIdx.x >> 6;
    const int rg   = lane >> 3;                    // 0..7
    const int og   = lane & 7;                     // 0..7
    const int rowbase = blockIdx.x * 128;
    const int rr   = w * 32 + rg * 4;              // lane's first row within block
    const int r0   = rowbase + rr;

    float acc[4][8];
#pragma unroll
    for (int i = 0; i < 4; ++i)
#pragma unroll
        for (int j = 0; j < 8; ++j) acc[i][j] = 0.f;

    for (int kc = 0; kc < K; kc += CH) {
        __syncthreads();
        // stage 128 rows x CH k's, transposed: xs[k][row]
#pragma unroll
        for (int it = 0; it < 2; ++it) {
            int idx = it * 256 + threadIdx.x;      // 0..511
            int row = idx >> 2;                    // 0..127
            int q   = idx & 3;                     // k-quad
            int grow = rowbase + row; grow = grow < N ? grow : N - 1;
            float4 v = *(const float4*)&X[(size_t)grow * K + kc + q * 4];
            xs[(q * 4 + 0) * XS + row] = v.x;
            xs[(q * 4 + 1) * XS + row] = v.y;
            xs[(q * 4 + 2) * XS + row] = v.z;
            xs[(q * 4 + 3) * XS + row] = v.w;
        }
        __syncthreads();
#pragma unroll
        for (int k = 0; k < CH; ++k) {
            const float4 a  = *(const float4*)&xs[k * XS + rr];
            const float4 b0 = *(const float4*)&ws[(kc + k) * 64 + og * 8];
            const float4 b1 = *(const float4*)&ws[(kc + k) * 64 + og * 8 + 4];
            const float av[4]  = {a.x, a.y, a.z, a.w};
            const float bv8[8] = {b0.x, b0.y, b0.z, b0.w, b1.x, b1.y, b1.z, b1.w};
#pragma unroll
            for (int i = 0; i < 4; ++i)
#pragma unroll
                for (int j = 0; j < 8; ++j)
                    acc[i][j] = fmaf(av[i], bv8[j], acc[i][j]);
        }
    }

    if (SS) {
        float asv[8], adv[8];
        *(float4*)&asv[0] = *(const float4*)&a_s[og * 8];
        *(float4*)&asv[4] = *(const float4*)&a_s[og * 8 + 4];
        *(float4*)&adv[0] = *(const float4*)&a_d[og * 8];
        *(float4*)&adv[4] = *(const float4*)&a_d[og * 8 + 4];
#pragma unroll
        for (int i = 0; i < 4; ++i) {
            float s = 0.f, d = 0.f;
#pragma unroll
            for (int j = 0; j < 8; ++j) {
                s = fmaf(acc[i][j], asv[j], s);
                d = fmaf(acc[i][j], adv[j], d);
            }
            // reduce across the 8 og-lanes of this rg-octet
#pragma unroll
            for (int o = 1; o <= 4; o <<= 1) {
                s += __shfl_xor(s, o, 64);
                d += __shfl_xor(d, o, 64);
            }
            if (og == 0 && r0 + i < N) { ss[r0 + i] = s; sd[r0 + i] = d; }
        }
    }

    // epilogue store
#pragma unroll
    for (int i = 0; i < 4; ++i) {
        int r = r0 + i;
        if (r >= N) continue;
        if (OUTW == 64) {
            float4 o0 = make_float4(acc[i][0], acc[i][1], acc[i][2], acc[i][3]);
            float4 o1 = make_float4(acc[i][4], acc[i][5], acc[i][6], acc[i][7]);
            *(float4*)&H[(size_t)r * 64 + og * 8]     = o0;
            *(float4*)&H[(size_t)r * 64 + og * 8 + 4] = o1;
        } else {
#pragma unroll
            for (int j = 0; j < 8; ++j) {
                int o = og * 8 + j;
                if (o < OUTW) H[(size_t)r * OUTW + o] = acc[i][j] + bias[o];
            }
        }
    }
}

// ---------------- Aggregation: z[n] = elu( sum_j alpha_j h[src_j] + b ) ----------------
// one wave per dst node; lane = feature dim (HID=64).

__global__ __launch_bounds__(256) void k_agg(const int* __restrict__ rowptr, const int* __restrict__ csr,
                                             const float* __restrict__ ss, const float* __restrict__ sd,
                                             const float* __restrict__ h, const float* __restrict__ bias,
                                             float* __restrict__ z, int N) {
    __shared__ float2 ps[4 * CAP];
    int w = __builtin_amdgcn_readfirstlane((int)(threadIdx.x >> 6));
    int lane = (int)(threadIdx.x & 63);
    int n = blockIdx.x * 4 + w;
    if (n >= N) return;

    int ro = rowptr[n];
    int deg = rowptr[n + 1] - ro;
    float sdn = sd[n];
    float bv = bias[lane];
    float2* myps = ps + w * CAP;

    float acc = 0.f;
    float inv;

    if (deg <= CAP) {
        float m = -1e30f;
        for (int j = lane; j < deg; j += 64) {
            int s = csr[ro + j];
            float e = ss[s] + sdn;
            e = (e >= 0.f) ? e : NEG_SLOPE * e;
            myps[j] = make_float2(e, __int_as_float(s));
            m = fmaxf(m, e);
        }
        m = wred_max(m);
        float sum = 0.f;
        for (int j = lane; j < deg; j += 64) {
            float p = expf(myps[j].x - m);
            myps[j].x = p;
            sum += p;
        }
        sum = wred_sum(sum);
        inv = 1.f / (sum + 1e-16f);
        // 4x-unrolled weighted gather: 4 independent loads in flight
        float a0 = 0.f, a1 = 0.f, a2 = 0.f, a3 = 0.f;
        int j = 0;
        for (; j + 3 < deg; j += 4) {
            float2 p0 = myps[j], p1 = myps[j + 1], p2 = myps[j + 2], p3 = myps[j + 3];
            a0 = fmaf(p0.x, h[(size_t)__float_as_int(p0.y) * 64 + lane], a0);
            a1 = fmaf(p1.x, h[(size_t)__float_as_int(p1.y) * 64 + lane], a1);
            a2 = fmaf(p2.x, h[(size_t)__float_as_int(p2.y) * 64 + lane], a2);
            a3 = fmaf(p3.x, h[(size_t)__float_as_int(p3.y) * 64 + lane], a3);
        }
        for (; j < deg; ++j) {
            float2 p = myps[j];
            a0 = fmaf(p.x, h[(size_t)__float_as_int(p.y) * 64 + lane], a0);
        }
        acc = (a0 + a1) + (a2 + a3);
    } else {
        // recompute fallback (deg > CAP): statistically never taken, correctness-guarded
        float m = -1e30f;
        for (int j = lane; j < deg; j += 64) {
            int s = csr[ro + j];
            float e = ss[s] + sdn;
            e = (e >= 0.f) ? e : NEG_SLOPE * e;
            m = fmaxf(m, e);
        }
        m = wred_max(m);
        float sum = 0.f;
        for (int j = lane; j < deg; j += 64) {
            int s = csr[ro + j];
            float e = ss[s] + sdn;
            e = (e >= 0.f) ? e : NEG_SLOPE * e;
            sum += expf(e - m);
        }
        sum = wred_sum(sum);
        inv = 1.f / (sum + 1e-16f);
        for (int j = 0; j < deg; ++j) {
            int s = csr[ro + j];
            float e = ss[s] + sdn;
            e = (e >= 0.f) ? e : NEG_SLOPE * e;
            float p = expf(e - m);
            acc = fmaf(p, h[(size_t)s * 64 + lane], acc);
        }
    }

    float o = acc * inv + bv;
    z[(size_t)n * 64 + lane] = (o > 0.f) ? o : expm1f(o);
}

// ---------------- launch ----------------

extern "C" void kernel_launch(void* const* d_in, const int* in_sizes, int n_in,
                              void* d_out, int out_size, void* d_ws, size_t ws_size,
                              hipStream_t stream) {
    const float* x   = (const float*)d_in[0];
    const int*   ei  = (const int*)d_in[1];
    const float* W0  = (const float*)d_in[2];
    const float* as0 = (const float*)d_in[3];
    const float* ad0 = (const float*)d_in[4];
    const float* b0  = (const float*)d_in[5];
    const float* W1  = (const float*)d_in[6];
    const float* as1 = (const float*)d_in[7];
    const float* ad1 = (const float*)d_in[8];
    const float* b1  = (const float*)d_in[9];
    const float* Wl  = (const float*)d_in[10];
    const float* bl  = (const float*)d_in[11];
    float* out = (float*)d_out;

    int N = in_sizes[0] / 128;
    int E = in_sizes[1] / 2;
    const int* srcp = ei;
    const int* dstp = ei + E;

    char* wp = (char*)d_ws;
    auto alloc = [&](size_t bytes) { void* p = (void*)wp; wp += (bytes + 255) & ~(size_t)255; return p; };
    float* h      = (float*)alloc((size_t)N * 64 * 4);
    float* z      = (float*)alloc((size_t)N * 64 * 4);
    float* ssb    = (float*)alloc((size_t)N * 4);
    float* sdb    = (float*)alloc((size_t)N * 4);
    int*   deg    = (int*)alloc((size_t)N * 4);
    int*   cursor = (int*)alloc((size_t)N * 4);
    int*   rowptr = (int*)alloc((size_t)(N + 1) * 4);
    int*   bsums  = (int*)alloc(1024 * 4);
    int*   csr    = (int*)alloc((size_t)(E + N) * 4);

    int nb = (N + 1023) / 1024;

    k_init<<<(N + 255) / 256, 256, 0, stream>>>(deg, N);
    k_count<<<(E + 1023) / 1024, 256, 0, stream>>>(dstp, deg, E);
    k_scan1<<<nb, 256, 0, stream>>>(deg, rowptr, bsums, N);
    k_scan2<<<1, 1024, 0, stream>>>(bsums, nb, rowptr, N, E + N);
    k_scan3<<<(N + 255) / 256, 256, 0, stream>>>(rowptr, bsums, cursor, N);
    k_fill<<<(E + N + 1023) / 1024, 256, 0, stream>>>(srcp, dstp, cursor, csr, E, N);

    int gb = (N + 127) / 128;
    // layer 0: h = x @ W0 ; ss/sd ; aggregate+elu -> z
    k_gemm<128, 64, true><<<gb, 256, 0, stream>>>(x, W0, as0, ad0, nullptr, h, ssb, sdb, N);
    k_agg<<<(N + 3) / 4, 256, 0, stream>>>(rowptr, csr, ssb, sdb, h, b0, z, N);

    // layer 1: h = z @ W1 ; ss/sd ; aggregate+elu -> z (h reused)
    k_gemm<64, 64, true><<<gb, 256, 0, stream>>>(z, W1, as1, ad1, nullptr, h, ssb, sdb, N);
    k_agg<<<(N + 3) / 4, 256, 0, stream>>>(rowptr, csr, ssb, sdb, h, b1, z, N);

    // classifier: out = z @ Wl + bl
    k_gemm<64, 40, false><<<gb, 256, 0, stream>>>(z, Wl, nullptr, nullptr, bl, out, nullptr, nullptr, N);
}

// Round 3
// 387.415 us; speedup vs baseline: 1.4956x; 1.3868x over previous
//
#include <hip/hip_runtime.h>
#include <math.h>

#define NEG_SLOPE 0.2f
#define CAP 256     // max degree on the agg fast path
#define BSH 9       // node-bucket shift: 512 nodes/bucket
#define BSZ 512
#define CHUNK 8192  // edges per k_scatter block

__device__ __forceinline__ float wred_sum(float v) {
#pragma unroll
    for (int o = 32; o >= 1; o >>= 1) v += __shfl_xor(v, o, 64);
    return v;
}
__device__ __forceinline__ float wred_max(float v) {
#pragma unroll
    for (int o = 32; o >= 1; o >>= 1) v = fmaxf(v, __shfl_xor(v, o, 64));
    return v;
}

// ---------------- CSR build: bucketed counting sort ----------------

__global__ __launch_bounds__(256) void k_zero(int* p, int n) {
    int i = blockIdx.x * 256 + threadIdx.x;
    if (i < n) p[i] = 0;
}

// bucket histogram of dst
__global__ __launch_bounds__(256) void k_hist(const int* __restrict__ dst, int* __restrict__ bcount, int E) {
    __shared__ int lh[256];
    lh[threadIdx.x] = 0;
    __syncthreads();
    int stride = gridDim.x * 256;
    for (int i = blockIdx.x * 256 + threadIdx.x; i < E; i += stride)
        atomicAdd(&lh[dst[i] >> BSH], 1);
    __syncthreads();
    int c = lh[threadIdx.x];
    if (c) atomicAdd(&bcount[threadIdx.x], c);
}

// single block: exclusive scans of bcount (edge buffer) and bcount+nodes (csr)
__global__ __launch_bounds__(256) void k_bscan(const int* __restrict__ bcount,
                                               int* __restrict__ eoff, int* __restrict__ boff,
                                               int* __restrict__ bcursor, int* __restrict__ rowptr,
                                               int nbuck, int N, int E) {
    __shared__ int s1[256], s2[256];
    int t = threadIdx.x;
    int bc = (t < nbuck) ? bcount[t] : 0;
    int cn = 0;
    if (t < nbuck) { cn = N - (t << BSH); if (cn > BSZ) cn = BSZ; if (cn < 0) cn = 0; }
    int tot = bc + cn;
    s1[t] = bc; s2[t] = tot;
    __syncthreads();
#pragma unroll
    for (int off = 1; off < 256; off <<= 1) {
        int u1 = (t >= off) ? s1[t - off] : 0;
        int u2 = (t >= off) ? s2[t - off] : 0;
        __syncthreads();
        s1[t] += u1; s2[t] += u2;
        __syncthreads();
    }
    if (t < nbuck) {
        int e = s1[t] - bc, b = s2[t] - tot;
        eoff[t] = e; boff[t] = b; bcursor[t] = e;
    }
    if (t == 0) rowptr[N] = E + N;
}

// scatter edges into bucket-grouped ebuf; per-block burst reservation for write combining
__global__ __launch_bounds__(256) void k_scatter(const int* __restrict__ src, const int* __restrict__ dst,
                                                 int* __restrict__ bcursor, int* __restrict__ ebuf, int E) {
    __shared__ int lh[256], lb[256];
    int base = blockIdx.x * CHUNK;
    int end = base + CHUNK; if (end > E) end = E;
    lh[threadIdx.x] = 0;
    __syncthreads();
    for (int i = base + threadIdx.x; i < end; i += 256)
        atomicAdd(&lh[dst[i] >> BSH], 1);
    __syncthreads();
    int c = lh[threadIdx.x];
    lb[threadIdx.x] = c ? atomicAdd(&bcursor[threadIdx.x], c) : 0;
    lh[threadIdx.x] = 0;
    __syncthreads();
    for (int i = base + threadIdx.x; i < end; i += 256) {
        int d = dst[i], b = d >> BSH;
        int p = atomicAdd(&lh[b], 1);
        ebuf[lb[b] + p] = (src[i] << BSH) | (d & (BSZ - 1));   // packed record
    }
}

// one block per bucket: LDS degree count + scan + cursor -> rowptr & csr (self-loop in slot 0)
__global__ __launch_bounds__(512) void k_build(const int* __restrict__ eoff, const int* __restrict__ boff,
                                               const int* __restrict__ bcount, const int* __restrict__ ebuf,
                                               int* __restrict__ rowptr, int* __restrict__ csr, int N) {
    __shared__ int sdeg[BSZ], sscan[BSZ];
    int b = blockIdx.x, t = threadIdx.x;
    int nlo = b << BSH;
    int cn = N - nlo; if (cn > BSZ) cn = BSZ;
    int e0 = eoff[b], ec = bcount[b], cb = boff[b];
    sdeg[t] = (t < cn) ? 1 : 0;      // self-loop
    __syncthreads();
    for (int i = t; i < ec; i += 512)
        atomicAdd(&sdeg[ebuf[e0 + i] & (BSZ - 1)], 1);
    __syncthreads();
    int v = sdeg[t];
    sscan[t] = v;
    __syncthreads();
#pragma unroll
    for (int off = 1; off < BSZ; off <<= 1) {
        int u = (t >= off) ? sscan[t - off] : 0;
        __syncthreads();
        sscan[t] += u;
        __syncthreads();
    }
    int excl = sscan[t] - v;
    if (t < cn) {
        rowptr[nlo + t] = cb + excl;
        csr[cb + excl] = nlo + t;    // self-loop first
        sdeg[t] = excl + 1;          // cursor
    }
    __syncthreads();
    for (int i = t; i < ec; i += 512) {
        int rec = ebuf[e0 + i];
        int p = atomicAdd(&sdeg[rec & (BSZ - 1)], 1);
        csr[cb + p] = rec >> BSH;
    }
}

// ---------------- GEMM: H = X @ W (+bias), optionally ss = H a_s, sd = H a_d ----
// block = 256 (4 waves), 128 rows/block. Lane tile: 4 rows x 8 cols (compute width
// fixed 64; W zero-padded for OUTW<64). X chunk staged transposed in LDS.

template <int K, int OUTW, bool SS>
__global__ __launch_bounds__(256) void k_gemm(const float* __restrict__ X,
                                              const float* __restrict__ W,
                                              const float* __restrict__ a_s,
                                              const float* __restrict__ a_d,
                                              const float* __restrict__ bias,
                                              float* __restrict__ H,
                                              float* __restrict__ ss,
                                              float* __restrict__ sd, int N) {
    constexpr int CH = 16;             // k-chunk
    constexpr int XS = 132;            // xs row stride in words (128 + 4 pad)
    __shared__ __align__(16) float ws[K * 64];
    __shared__ __align__(16) float xs[CH * XS];

    if (OUTW == 64) {
        for (int i = threadIdx.x * 4; i < K * 64; i += 1024)
            *(float4*)&ws[i] = *(const float4*)&W[i];
    } else {
        for (int i = threadIdx.x; i < K * 64; i += 256) {
            int k = i >> 6, o = i & 63;
            ws[i] = (o < OUTW) ? W[k * OUTW + o] : 0.f;
        }
    }

    const int lane = threadIdx.x & 63;
    const int w    = threadIdx.x >> 6;
    const int rg   = lane >> 3;                    // 0..7
    const int og   = lane & 7;                     // 0..7
    const int rowbase = blockIdx.x * 128;
    const int rr   = w * 32 + rg * 4;
    const int r0   = rowbase + rr;

    float acc[4][8];
#pragma unroll
    for (int i = 0; i < 4; ++i)
#pragma unroll
        for (int j = 0; j < 8; ++j) acc[i][j] = 0.f;

    for (int kc = 0; kc < K; kc += CH) {
        __syncthreads();
#pragma unroll
        for (int it = 0; it < 2; ++it) {
            int idx = it * 256 + threadIdx.x;
            int row = idx >> 2;
            int q   = idx & 3;
            int grow = rowbase + row; grow = grow < N ? grow : N - 1;
            float4 v = *(const float4*)&X[(size_t)grow * K + kc + q * 4];
            xs[(q * 4 + 0) * XS + row] = v.x;
            xs[(q * 4 + 1) * XS + row] = v.y;
            xs[(q * 4 + 2) * XS + row] = v.z;
            xs[(q * 4 + 3) * XS + row] = v.w;
        }
        __syncthreads();
#pragma unroll
        for (int k = 0; k < CH; ++k) {
            const float4 a  = *(const float4*)&xs[k * XS + rr];
            const float4 b0 = *(const float4*)&ws[(kc + k) * 64 + og * 8];
            const float4 b1 = *(const float4*)&ws[(kc + k) * 64 + og * 8 + 4];
            const float av[4]  = {a.x, a.y, a.z, a.w};
            const float bv8[8] = {b0.x, b0.y, b0.z, b0.w, b1.x, b1.y, b1.z, b1.w};
#pragma unroll
            for (int i = 0; i < 4; ++i)
#pragma unroll
                for (int j = 0; j < 8; ++j)
                    acc[i][j] = fmaf(av[i], bv8[j], acc[i][j]);
        }
    }

    if (SS) {
        float asv[8], adv[8];
        *(float4*)&asv[0] = *(const float4*)&a_s[og * 8];
        *(float4*)&asv[4] = *(const float4*)&a_s[og * 8 + 4];
        *(float4*)&adv[0] = *(const float4*)&a_d[og * 8];
        *(float4*)&adv[4] = *(const float4*)&a_d[og * 8 + 4];
#pragma unroll
        for (int i = 0; i < 4; ++i) {
            float s = 0.f, d = 0.f;
#pragma unroll
            for (int j = 0; j < 8; ++j) {
                s = fmaf(acc[i][j], asv[j], s);
                d = fmaf(acc[i][j], adv[j], d);
            }
#pragma unroll
            for (int o = 1; o <= 4; o <<= 1) {
                s += __shfl_xor(s, o, 64);
                d += __shfl_xor(d, o, 64);
            }
            if (og == 0 && r0 + i < N) { ss[r0 + i] = s; sd[r0 + i] = d; }
        }
    }

#pragma unroll
    for (int i = 0; i < 4; ++i) {
        int r = r0 + i;
        if (r >= N) continue;
        if (OUTW == 64) {
            float4 o0 = make_float4(acc[i][0], acc[i][1], acc[i][2], acc[i][3]);
            float4 o1 = make_float4(acc[i][4], acc[i][5], acc[i][6], acc[i][7]);
            *(float4*)&H[(size_t)r * 64 + og * 8]     = o0;
            *(float4*)&H[(size_t)r * 64 + og * 8 + 4] = o1;
        } else {
#pragma unroll
            for (int j = 0; j < 8; ++j) {
                int o = og * 8 + j;
                if (o < OUTW) H[(size_t)r * OUTW + o] = acc[i][j] + bias[o];
            }
        }
    }
}

// ---------------- Aggregation: z[n] = elu( sum_j alpha_j h[src_j] + b ) ------

__global__ __launch_bounds__(256) void k_agg(const int* __restrict__ rowptr, const int* __restrict__ csr,
                                             const float* __restrict__ ss, const float* __restrict__ sd,
                                             const float* __restrict__ h, const float* __restrict__ bias,
                                             float* __restrict__ z, int N) {
    __shared__ float2 ps[4 * CAP];
    int w = __builtin_amdgcn_readfirstlane((int)(threadIdx.x >> 6));
    int lane = (int)(threadIdx.x & 63);
    int n = blockIdx.x * 4 + w;
    if (n >= N) return;

    int ro = rowptr[n];
    int deg = rowptr[n + 1] - ro;
    float sdn = sd[n];
    float bv = bias[lane];
    float2* myps = ps + w * CAP;

    float acc = 0.f;
    float inv;

    if (deg <= CAP) {
        float m = -1e30f;
        for (int j = lane; j < deg; j += 64) {
            int s = csr[ro + j];
            float e = ss[s] + sdn;
            e = (e >= 0.f) ? e : NEG_SLOPE * e;
            myps[j] = make_float2(e, __int_as_float(s));
            m = fmaxf(m, e);
        }
        m = wred_max(m);
        float sum = 0.f;
        for (int j = lane; j < deg; j += 64) {
            float p = expf(myps[j].x - m);
            myps[j].x = p;
            sum += p;
        }
        sum = wred_sum(sum);
        inv = 1.f / (sum + 1e-16f);
        float a0 = 0.f, a1 = 0.f, a2 = 0.f, a3 = 0.f;
        int j = 0;
        for (; j + 3 < deg; j += 4) {
            float2 p0 = myps[j], p1 = myps[j + 1], p2 = myps[j + 2], p3 = myps[j + 3];
            a0 = fmaf(p0.x, h[(size_t)__float_as_int(p0.y) * 64 + lane], a0);
            a1 = fmaf(p1.x, h[(size_t)__float_as_int(p1.y) * 64 + lane], a1);
            a2 = fmaf(p2.x, h[(size_t)__float_as_int(p2.y) * 64 + lane], a2);
            a3 = fmaf(p3.x, h[(size_t)__float_as_int(p3.y) * 64 + lane], a3);
        }
        for (; j < deg; ++j) {
            float2 p = myps[j];
            a0 = fmaf(p.x, h[(size_t)__float_as_int(p.y) * 64 + lane], a0);
        }
        acc = (a0 + a1) + (a2 + a3);
    } else {
        float m = -1e30f;
        for (int j = lane; j < deg; j += 64) {
            int s = csr[ro + j];
            float e = ss[s] + sdn;
            e = (e >= 0.f) ? e : NEG_SLOPE * e;
            m = fmaxf(m, e);
        }
        m = wred_max(m);
        float sum = 0.f;
        for (int j = lane; j < deg; j += 64) {
            int s = csr[ro + j];
            float e = ss[s] + sdn;
            e = (e >= 0.f) ? e : NEG_SLOPE * e;
            sum += expf(e - m);
        }
        sum = wred_sum(sum);
        inv = 1.f / (sum + 1e-16f);
        for (int j = 0; j < deg; ++j) {
            int s = csr[ro + j];
            float e = ss[s] + sdn;
            e = (e >= 0.f) ? e : NEG_SLOPE * e;
            float p = expf(e - m);
            acc = fmaf(p, h[(size_t)s * 64 + lane], acc);
        }
    }

    float o = acc * inv + bv;
    z[(size_t)n * 64 + lane] = (o > 0.f) ? o : expm1f(o);
}

// ---------------- launch ----------------

extern "C" void kernel_launch(void* const* d_in, const int* in_sizes, int n_in,
                              void* d_out, int out_size, void* d_ws, size_t ws_size,
                              hipStream_t stream) {
    const float* x   = (const float*)d_in[0];
    const int*   ei  = (const int*)d_in[1];
    const float* W0  = (const float*)d_in[2];
    const float* as0 = (const float*)d_in[3];
    const float* ad0 = (const float*)d_in[4];
    const float* b0  = (const float*)d_in[5];
    const float* W1  = (const float*)d_in[6];
    const float* as1 = (const float*)d_in[7];
    const float* ad1 = (const float*)d_in[8];
    const float* b1  = (const float*)d_in[9];
    const float* Wl  = (const float*)d_in[10];
    const float* bl  = (const float*)d_in[11];
    float* out = (float*)d_out;

    int N = in_sizes[0] / 128;
    int E = in_sizes[1] / 2;
    const int* srcp = ei;
    const int* dstp = ei + E;
    int nbuck = (N + BSZ - 1) >> BSH;    // 196 for N=100000 (must be <= 256)

    char* wp = (char*)d_ws;
    auto alloc = [&](size_t bytes) { void* p = (void*)wp; wp += (bytes + 255) & ~(size_t)255; return p; };
    float* h       = (float*)alloc((size_t)N * 64 * 4);
    float* z       = (float*)alloc((size_t)N * 64 * 4);
    float* ssb     = (float*)alloc((size_t)N * 4);
    float* sdb     = (float*)alloc((size_t)N * 4);
    int*   rowptr  = (int*)alloc((size_t)(N + 1) * 4);
    int*   csr     = (int*)alloc((size_t)(E + N) * 4);
    int*   ebuf    = (int*)alloc((size_t)E * 4);
    int*   bcount  = (int*)alloc(256 * 4);
    int*   eoff    = (int*)alloc(256 * 4);
    int*   boff    = (int*)alloc(256 * 4);
    int*   bcursor = (int*)alloc(256 * 4);

    // CSR build
    k_zero<<<1, 256, 0, stream>>>(bcount, 256);
    k_hist<<<256, 256, 0, stream>>>(dstp, bcount, E);
    k_bscan<<<1, 256, 0, stream>>>(bcount, eoff, boff, bcursor, rowptr, nbuck, N, E);
    k_scatter<<<(E + CHUNK - 1) / CHUNK, 256, 0, stream>>>(srcp, dstp, bcursor, ebuf, E);
    k_build<<<nbuck, 512, 0, stream>>>(eoff, boff, bcount, ebuf, rowptr, csr, N);

    int gb = (N + 127) / 128;
    // layer 0
    k_gemm<128, 64, true><<<gb, 256, 0, stream>>>(x, W0, as0, ad0, nullptr, h, ssb, sdb, N);
    k_agg<<<(N + 3) / 4, 256, 0, stream>>>(rowptr, csr, ssb, sdb, h, b0, z, N);
    // layer 1
    k_gemm<64, 64, true><<<gb, 256, 0, stream>>>(z, W1, as1, ad1, nullptr, h, ssb, sdb, N);
    k_agg<<<(N + 3) / 4, 256, 0, stream>>>(rowptr, csr, ssb, sdb, h, b1, z, N);
    // classifier
    k_gemm<64, 40, false><<<gb, 256, 0, stream>>>(z, Wl, nullptr, nullptr, bl, out, nullptr, nullptr, N);
}

// Round 4
// 352.827 us; speedup vs baseline: 1.6422x; 1.0980x over previous
//
#include <hip/hip_runtime.h>
#include <math.h>

#define NEG_SLOPE 0.2f
#define CAP 256     // max degree on the agg fast path
#define BSH 9       // node-bucket shift: 512 nodes/bucket
#define BSZ 512
#define CHUNK 8192  // edges per k_scatter block

__device__ __forceinline__ float wred_sum(float v) {
#pragma unroll
    for (int o = 32; o >= 1; o >>= 1) v += __shfl_xor(v, o, 64);
    return v;
}
__device__ __forceinline__ float wred_max(float v) {
#pragma unroll
    for (int o = 32; o >= 1; o >>= 1) v = fmaxf(v, __shfl_xor(v, o, 64));
    return v;
}
// fp32 -> bf16 (RNE), and bf16(lo/hi of uint) -> fp32
__device__ __forceinline__ unsigned int f2bf(float f) {
    unsigned int u = __float_as_uint(f);
    return (u + 0x7fffu + ((u >> 16) & 1u)) >> 16;
}
__device__ __forceinline__ float bflo(unsigned int u) { return __uint_as_float(u << 16); }
__device__ __forceinline__ float bfhi(unsigned int u) { return __uint_as_float(u & 0xffff0000u); }

// ---------------- CSR build: bucketed counting sort ----------------

__global__ __launch_bounds__(256) void k_zero(int* p, int n) {
    int i = blockIdx.x * 256 + threadIdx.x;
    if (i < n) p[i] = 0;
}

__global__ __launch_bounds__(256) void k_hist(const int* __restrict__ dst, int* __restrict__ bcount, int E) {
    __shared__ int lh[256];
    lh[threadIdx.x] = 0;
    __syncthreads();
    int stride = gridDim.x * 256;
    for (int i = blockIdx.x * 256 + threadIdx.x; i < E; i += stride)
        atomicAdd(&lh[dst[i] >> BSH], 1);
    __syncthreads();
    int c = lh[threadIdx.x];
    if (c) atomicAdd(&bcount[threadIdx.x], c);
}

__global__ __launch_bounds__(256) void k_bscan(const int* __restrict__ bcount,
                                               int* __restrict__ eoff, int* __restrict__ boff,
                                               int* __restrict__ bcursor, int* __restrict__ rowptr,
                                               int nbuck, int N, int E) {
    __shared__ int s1[256], s2[256];
    int t = threadIdx.x;
    int bc = (t < nbuck) ? bcount[t] : 0;
    int cn = 0;
    if (t < nbuck) { cn = N - (t << BSH); if (cn > BSZ) cn = BSZ; if (cn < 0) cn = 0; }
    int tot = bc + cn;
    s1[t] = bc; s2[t] = tot;
    __syncthreads();
#pragma unroll
    for (int off = 1; off < 256; off <<= 1) {
        int u1 = (t >= off) ? s1[t - off] : 0;
        int u2 = (t >= off) ? s2[t - off] : 0;
        __syncthreads();
        s1[t] += u1; s2[t] += u2;
        __syncthreads();
    }
    if (t < nbuck) {
        int e = s1[t] - bc, b = s2[t] - tot;
        eoff[t] = e; boff[t] = b; bcursor[t] = e;
    }
    if (t == 0) rowptr[N] = E + N;
}

__global__ __launch_bounds__(256) void k_scatter(const int* __restrict__ src, const int* __restrict__ dst,
                                                 int* __restrict__ bcursor, int* __restrict__ ebuf, int E) {
    __shared__ int lh[256], lb[256];
    int base = blockIdx.x * CHUNK;
    int end = base + CHUNK; if (end > E) end = E;
    lh[threadIdx.x] = 0;
    __syncthreads();
    for (int i = base + threadIdx.x; i < end; i += 256)
        atomicAdd(&lh[dst[i] >> BSH], 1);
    __syncthreads();
    int c = lh[threadIdx.x];
    lb[threadIdx.x] = c ? atomicAdd(&bcursor[threadIdx.x], c) : 0;
    lh[threadIdx.x] = 0;
    __syncthreads();
    for (int i = base + threadIdx.x; i < end; i += 256) {
        int d = dst[i], b = d >> BSH;
        int p = atomicAdd(&lh[b], 1);
        ebuf[lb[b] + p] = (src[i] << BSH) | (d & (BSZ - 1));
    }
}

__global__ __launch_bounds__(512) void k_build(const int* __restrict__ eoff, const int* __restrict__ boff,
                                               const int* __restrict__ bcount, const int* __restrict__ ebuf,
                                               int* __restrict__ rowptr, int* __restrict__ csr, int N) {
    __shared__ int sdeg[BSZ], sscan[BSZ];
    int b = blockIdx.x, t = threadIdx.x;
    int nlo = b << BSH;
    int cn = N - nlo; if (cn > BSZ) cn = BSZ;
    int e0 = eoff[b], ec = bcount[b], cb = boff[b];
    sdeg[t] = (t < cn) ? 1 : 0;
    __syncthreads();
    for (int i = t; i < ec; i += 512)
        atomicAdd(&sdeg[ebuf[e0 + i] & (BSZ - 1)], 1);
    __syncthreads();
    int v = sdeg[t];
    sscan[t] = v;
    __syncthreads();
#pragma unroll
    for (int off = 1; off < BSZ; off <<= 1) {
        int u = (t >= off) ? sscan[t - off] : 0;
        __syncthreads();
        sscan[t] += u;
        __syncthreads();
    }
    int excl = sscan[t] - v;
    if (t < cn) {
        rowptr[nlo + t] = cb + excl;
        csr[cb + excl] = nlo + t;
        sdeg[t] = excl + 1;
    }
    __syncthreads();
    for (int i = t; i < ec; i += 512) {
        int rec = ebuf[e0 + i];
        int p = atomicAdd(&sdeg[rec & (BSZ - 1)], 1);
        csr[cb + p] = rec >> BSH;
    }
}

// ---------------- GEMM: H = X @ W (+bias), optional ss/sd, optional bf16 H ----

template <int K, int OUTW, bool SS, bool HB>
__global__ __launch_bounds__(256) void k_gemm(const float* __restrict__ X,
                                              const float* __restrict__ W,
                                              const float* __restrict__ a_s,
                                              const float* __restrict__ a_d,
                                              const float* __restrict__ bias,
                                              void* __restrict__ Hout,
                                              float* __restrict__ ss,
                                              float* __restrict__ sd, int N) {
    constexpr int CH = 16;
    constexpr int XS = 132;
    __shared__ __align__(16) float ws[K * 64];
    __shared__ __align__(16) float xs[CH * XS];

    if (OUTW == 64) {
        for (int i = threadIdx.x * 4; i < K * 64; i += 1024)
            *(float4*)&ws[i] = *(const float4*)&W[i];
    } else {
        for (int i = threadIdx.x; i < K * 64; i += 256) {
            int k = i >> 6, o = i & 63;
            ws[i] = (o < OUTW) ? W[k * OUTW + o] : 0.f;
        }
    }

    const int lane = threadIdx.x & 63;
    const int w    = threadIdx.x >> 6;
    const int rg   = lane >> 3;
    const int og   = lane & 7;
    const int rowbase = blockIdx.x * 128;
    const int rr   = w * 32 + rg * 4;
    const int r0   = rowbase + rr;

    float acc[4][8];
#pragma unroll
    for (int i = 0; i < 4; ++i)
#pragma unroll
        for (int j = 0; j < 8; ++j) acc[i][j] = 0.f;

    for (int kc = 0; kc < K; kc += CH) {
        __syncthreads();
#pragma unroll
        for (int it = 0; it < 2; ++it) {
            int idx = it * 256 + threadIdx.x;
            int row = idx >> 2;
            int q   = idx & 3;
            int grow = rowbase + row; grow = grow < N ? grow : N - 1;
            float4 v = *(const float4*)&X[(size_t)grow * K + kc + q * 4];
            xs[(q * 4 + 0) * XS + row] = v.x;
            xs[(q * 4 + 1) * XS + row] = v.y;
            xs[(q * 4 + 2) * XS + row] = v.z;
            xs[(q * 4 + 3) * XS + row] = v.w;
        }
        __syncthreads();
#pragma unroll
        for (int k = 0; k < CH; ++k) {
            const float4 a  = *(const float4*)&xs[k * XS + rr];
            const float4 b0 = *(const float4*)&ws[(kc + k) * 64 + og * 8];
            const float4 b1 = *(const float4*)&ws[(kc + k) * 64 + og * 8 + 4];
            const float av[4]  = {a.x, a.y, a.z, a.w};
            const float bv8[8] = {b0.x, b0.y, b0.z, b0.w, b1.x, b1.y, b1.z, b1.w};
#pragma unroll
            for (int i = 0; i < 4; ++i)
#pragma unroll
                for (int j = 0; j < 8; ++j)
                    acc[i][j] = fmaf(av[i], bv8[j], acc[i][j]);
        }
    }

    if (SS) {
        float asv[8], adv[8];
        *(float4*)&asv[0] = *(const float4*)&a_s[og * 8];
        *(float4*)&asv[4] = *(const float4*)&a_s[og * 8 + 4];
        *(float4*)&adv[0] = *(const float4*)&a_d[og * 8];
        *(float4*)&adv[4] = *(const float4*)&a_d[og * 8 + 4];
#pragma unroll
        for (int i = 0; i < 4; ++i) {
            float s = 0.f, d = 0.f;
#pragma unroll
            for (int j = 0; j < 8; ++j) {
                s = fmaf(acc[i][j], asv[j], s);
                d = fmaf(acc[i][j], adv[j], d);
            }
#pragma unroll
            for (int o = 1; o <= 4; o <<= 1) {
                s += __shfl_xor(s, o, 64);
                d += __shfl_xor(d, o, 64);
            }
            if (og == 0 && r0 + i < N) { ss[r0 + i] = s; sd[r0 + i] = d; }
        }
    }

#pragma unroll
    for (int i = 0; i < 4; ++i) {
        int r = r0 + i;
        if (r >= N) continue;
        if (HB) {
            unsigned int* hb = (unsigned int*)Hout;
            uint4 u;
            u.x = (f2bf(acc[i][1]) << 16) | f2bf(acc[i][0]);
            u.y = (f2bf(acc[i][3]) << 16) | f2bf(acc[i][2]);
            u.z = (f2bf(acc[i][5]) << 16) | f2bf(acc[i][4]);
            u.w = (f2bf(acc[i][7]) << 16) | f2bf(acc[i][6]);
            *(uint4*)&hb[(size_t)r * 32 + og * 4] = u;
        } else if (OUTW == 64) {
            float* H = (float*)Hout;
            float4 o0 = make_float4(acc[i][0], acc[i][1], acc[i][2], acc[i][3]);
            float4 o1 = make_float4(acc[i][4], acc[i][5], acc[i][6], acc[i][7]);
            *(float4*)&H[(size_t)r * 64 + og * 8]     = o0;
            *(float4*)&H[(size_t)r * 64 + og * 8 + 4] = o1;
        } else {
            float* H = (float*)Hout;
#pragma unroll
            for (int j = 0; j < 8; ++j) {
                int o = og * 8 + j;
                if (o < OUTW) H[(size_t)r * OUTW + o] = acc[i][j] + bias[o];
            }
        }
    }
}

// ---------------- Aggregation: z[n] = elu( sum_j alpha_j h[src_j] + b ) ------
// one wave per dst node. h is bf16-packed (32 uints/row); gather phase reads
// 2 edges per wave-load: lanes 0-31 = edge j, lanes 32-63 = edge j+1.

__global__ __launch_bounds__(256) void k_agg(const int* __restrict__ rowptr, const int* __restrict__ csr,
                                             const float* __restrict__ ss, const float* __restrict__ sd,
                                             const unsigned int* __restrict__ hb, const float* __restrict__ bias,
                                             float* __restrict__ z, int N) {
    __shared__ float2 ps[4 * CAP];
    int w = __builtin_amdgcn_readfirstlane((int)(threadIdx.x >> 6));
    int lane = (int)(threadIdx.x & 63);
    int n = blockIdx.x * 4 + w;
    if (n >= N) return;

    int ro = rowptr[n];
    int deg = rowptr[n + 1] - ro;
    float sdn = sd[n];
    float2* myps = ps + w * CAP;

    if (deg <= CAP) {
        float m = -1e30f;
        for (int j = lane; j < deg; j += 64) {
            int s = csr[ro + j];
            float e = ss[s] + sdn;
            e = fmaxf(e, NEG_SLOPE * e);
            myps[j] = make_float2(e, __int_as_float(s));
            m = fmaxf(m, e);
        }
        m = wred_max(m);
        float sum = 0.f;
        for (int j = lane; j < deg; j += 64) {
            float p = __expf(myps[j].x - m);
            myps[j].x = p;
            sum += p;
        }
        sum = wred_sum(sum);
        float inv = 1.f / (sum + 1e-16f);
        if (deg & 1) {
            if (lane == 0) myps[deg] = make_float2(0.f, __int_as_float(n));
        }
        int deg2 = deg + (deg & 1);

        int par = lane >> 5;
        int p   = lane & 31;
        float ax = 0.f, ay = 0.f, bx = 0.f, by = 0.f, cx = 0.f, cy = 0.f, dx = 0.f, dy = 0.f;
        int j = 0;
        for (; j + 7 < deg2; j += 8) {
            float2 e0 = myps[j + par];
            float2 e1 = myps[j + 2 + par];
            float2 e2 = myps[j + 4 + par];
            float2 e3 = myps[j + 6 + par];
            unsigned int u0 = hb[(size_t)__float_as_int(e0.y) * 32 + p];
            unsigned int u1 = hb[(size_t)__float_as_int(e1.y) * 32 + p];
            unsigned int u2 = hb[(size_t)__float_as_int(e2.y) * 32 + p];
            unsigned int u3 = hb[(size_t)__float_as_int(e3.y) * 32 + p];
            ax = fmaf(bflo(u0), e0.x, ax); ay = fmaf(bfhi(u0), e0.x, ay);
            bx = fmaf(bflo(u1), e1.x, bx); by = fmaf(bfhi(u1), e1.x, by);
            cx = fmaf(bflo(u2), e2.x, cx); cy = fmaf(bfhi(u2), e2.x, cy);
            dx = fmaf(bflo(u3), e3.x, dx); dy = fmaf(bfhi(u3), e3.x, dy);
        }
        for (; j < deg2; j += 2) {
            float2 e0 = myps[j + par];
            unsigned int u0 = hb[(size_t)__float_as_int(e0.y) * 32 + p];
            ax = fmaf(bflo(u0), e0.x, ax); ay = fmaf(bfhi(u0), e0.x, ay);
        }
        float fx = (ax + bx) + (cx + dx);
        float fy = (ay + by) + (cy + dy);
        fx += __shfl_xor(fx, 32, 64);
        fy += __shfl_xor(fy, 32, 64);
        float2 ob = *(const float2*)&bias[p * 2];
        float ox = fmaf(fx, inv, ob.x);
        float oy = fmaf(fy, inv, ob.y);
        ox = (ox > 0.f) ? ox : expm1f(ox);
        oy = (oy > 0.f) ? oy : expm1f(oy);
        if (lane < 32) *(float2*)&z[(size_t)n * 64 + p * 2] = make_float2(ox, oy);
    } else {
        // fallback (deg > CAP): recompute path, lane = feature
        const unsigned short* hs = (const unsigned short*)hb;
        float m = -1e30f;
        for (int j = lane; j < deg; j += 64) {
            int s = csr[ro + j];
            float e = ss[s] + sdn;
            e = fmaxf(e, NEG_SLOPE * e);
            m = fmaxf(m, e);
        }
        m = wred_max(m);
        float sum = 0.f;
        for (int j = lane; j < deg; j += 64) {
            int s = csr[ro + j];
            float e = ss[s] + sdn;
            e = fmaxf(e, NEG_SLOPE * e);
            sum += __expf(e - m);
        }
        sum = wred_sum(sum);
        float inv = 1.f / (sum + 1e-16f);
        float acc = 0.f;
        for (int j = 0; j < deg; ++j) {
            int s = csr[ro + j];
            float e = ss[s] + sdn;
            e = fmaxf(e, NEG_SLOPE * e);
            float p = __expf(e - m);
            acc = fmaf(p, __uint_as_float(((unsigned int)hs[(size_t)s * 64 + lane]) << 16), acc);
        }
        float o = acc * inv + bias[lane];
        z[(size_t)n * 64 + lane] = (o > 0.f) ? o : expm1f(o);
    }
}

// ---------------- launch ----------------

extern "C" void kernel_launch(void* const* d_in, const int* in_sizes, int n_in,
                              void* d_out, int out_size, void* d_ws, size_t ws_size,
                              hipStream_t stream) {
    const float* x   = (const float*)d_in[0];
    const int*   ei  = (const int*)d_in[1];
    const float* W0  = (const float*)d_in[2];
    const float* as0 = (const float*)d_in[3];
    const float* ad0 = (const float*)d_in[4];
    const float* b0  = (const float*)d_in[5];
    const float* W1  = (const float*)d_in[6];
    const float* as1 = (const float*)d_in[7];
    const float* ad1 = (const float*)d_in[8];
    const float* b1  = (const float*)d_in[9];
    const float* Wl  = (const float*)d_in[10];
    const float* bl  = (const float*)d_in[11];
    float* out = (float*)d_out;

    int N = in_sizes[0] / 128;
    int E = in_sizes[1] / 2;
    const int* srcp = ei;
    const int* dstp = ei + E;
    int nbuck = (N + BSZ - 1) >> BSH;

    char* wp = (char*)d_ws;
    auto alloc = [&](size_t bytes) { void* p = (void*)wp; wp += (bytes + 255) & ~(size_t)255; return p; };
    unsigned int* hb = (unsigned int*)alloc((size_t)N * 32 * 4);   // bf16-packed h
    float* z       = (float*)alloc((size_t)N * 64 * 4);
    float* ssb     = (float*)alloc((size_t)N * 4);
    float* sdb     = (float*)alloc((size_t)N * 4);
    int*   rowptr  = (int*)alloc((size_t)(N + 1) * 4);
    int*   csr     = (int*)alloc((size_t)(E + N) * 4);
    int*   ebuf    = (int*)alloc((size_t)E * 4);
    int*   bcount  = (int*)alloc(256 * 4);
    int*   eoff    = (int*)alloc(256 * 4);
    int*   boff    = (int*)alloc(256 * 4);
    int*   bcursor = (int*)alloc(256 * 4);

    // CSR build
    k_zero<<<1, 256, 0, stream>>>(bcount, 256);
    k_hist<<<256, 256, 0, stream>>>(dstp, bcount, E);
    k_bscan<<<1, 256, 0, stream>>>(bcount, eoff, boff, bcursor, rowptr, nbuck, N, E);
    k_scatter<<<(E + CHUNK - 1) / CHUNK, 256, 0, stream>>>(srcp, dstp, bcursor, ebuf, E);
    k_build<<<nbuck, 512, 0, stream>>>(eoff, boff, bcount, ebuf, rowptr, csr, N);

    int gb = (N + 127) / 128;
    // layer 0
    k_gemm<128, 64, true, true><<<gb, 256, 0, stream>>>(x, W0, as0, ad0, nullptr, hb, ssb, sdb, N);
    k_agg<<<(N + 3) / 4, 256, 0, stream>>>(rowptr, csr, ssb, sdb, hb, b0, z, N);
    // layer 1
    k_gemm<64, 64, true, true><<<gb, 256, 0, stream>>>(z, W1, as1, ad1, nullptr, hb, ssb, sdb, N);
    k_agg<<<(N + 3) / 4, 256, 0, stream>>>(rowptr, csr, ssb, sdb, hb, b1, z, N);
    // classifier
    k_gemm<64, 40, false, false><<<gb, 256, 0, stream>>>(z, Wl, nullptr, nullptr, bl, out, nullptr, nullptr, N);
}

// Round 5
// 329.680 us; speedup vs baseline: 1.7575x; 1.0702x over previous
//
#include <hip/hip_runtime.h>
#include <math.h>

#define NEG_SLOPE 0.2f
#define CAP 256     // max degree on the agg fast path
#define BSH 9       // node-bucket shift: 512 nodes/bucket
#define BSZ 512
#define CHUNK 8192  // edges per k_scatter block

__device__ __forceinline__ float hred_sum(float v) {   // 32-wide (half-wave) reduce
#pragma unroll
    for (int o = 16; o >= 1; o >>= 1) v += __shfl_xor(v, o, 64);
    return v;
}
// fp32 -> bf16 (RNE), and bf16(lo/hi of uint) -> fp32
__device__ __forceinline__ unsigned int f2bf(float f) {
    unsigned int u = __float_as_uint(f);
    return (u + 0x7fffu + ((u >> 16) & 1u)) >> 16;
}
__device__ __forceinline__ float bflo(unsigned int u) { return __uint_as_float(u << 16); }
__device__ __forceinline__ float bfhi(unsigned int u) { return __uint_as_float(u & 0xffff0000u); }

// ---------------- CSR build: bucketed counting sort ----------------

__global__ __launch_bounds__(256) void k_zero(int* p, int n) {
    int i = blockIdx.x * 256 + threadIdx.x;
    if (i < n) p[i] = 0;
}

__global__ __launch_bounds__(256) void k_hist(const int* __restrict__ dst, int* __restrict__ bcount, int E) {
    __shared__ int lh[256];
    lh[threadIdx.x] = 0;
    __syncthreads();
    int stride = gridDim.x * 256;
    for (int i = blockIdx.x * 256 + threadIdx.x; i < E; i += stride)
        atomicAdd(&lh[dst[i] >> BSH], 1);
    __syncthreads();
    int c = lh[threadIdx.x];
    if (c) atomicAdd(&bcount[threadIdx.x], c);
}

__global__ __launch_bounds__(256) void k_bscan(const int* __restrict__ bcount,
                                               int* __restrict__ eoff, int* __restrict__ boff,
                                               int* __restrict__ bcursor, int* __restrict__ rowptr,
                                               int nbuck, int N, int E) {
    __shared__ int s1[256], s2[256];
    int t = threadIdx.x;
    int bc = (t < nbuck) ? bcount[t] : 0;
    int cn = 0;
    if (t < nbuck) { cn = N - (t << BSH); if (cn > BSZ) cn = BSZ; if (cn < 0) cn = 0; }
    int tot = bc + cn;
    s1[t] = bc; s2[t] = tot;
    __syncthreads();
#pragma unroll
    for (int off = 1; off < 256; off <<= 1) {
        int u1 = (t >= off) ? s1[t - off] : 0;
        int u2 = (t >= off) ? s2[t - off] : 0;
        __syncthreads();
        s1[t] += u1; s2[t] += u2;
        __syncthreads();
    }
    if (t < nbuck) {
        int e = s1[t] - bc, b = s2[t] - tot;
        eoff[t] = e; boff[t] = b; bcursor[t] = e;
    }
    if (t == 0) rowptr[N] = E + N;
}

__global__ __launch_bounds__(256) void k_scatter(const int* __restrict__ src, const int* __restrict__ dst,
                                                 int* __restrict__ bcursor, int* __restrict__ ebuf, int E) {
    __shared__ int lh[256], lb[256];
    int base = blockIdx.x * CHUNK;
    int end = base + CHUNK; if (end > E) end = E;
    lh[threadIdx.x] = 0;
    __syncthreads();
    for (int i = base + threadIdx.x; i < end; i += 256)
        atomicAdd(&lh[dst[i] >> BSH], 1);
    __syncthreads();
    int c = lh[threadIdx.x];
    lb[threadIdx.x] = c ? atomicAdd(&bcursor[threadIdx.x], c) : 0;
    lh[threadIdx.x] = 0;
    __syncthreads();
    for (int i = base + threadIdx.x; i < end; i += 256) {
        int d = dst[i], b = d >> BSH;
        int p = atomicAdd(&lh[b], 1);
        ebuf[lb[b] + p] = (src[i] << BSH) | (d & (BSZ - 1));
    }
}

__global__ __launch_bounds__(512) void k_build(const int* __restrict__ eoff, const int* __restrict__ boff,
                                               const int* __restrict__ bcount, const int* __restrict__ ebuf,
                                               int* __restrict__ rowptr, int* __restrict__ csr, int N) {
    __shared__ int sdeg[BSZ], sscan[BSZ];
    int b = blockIdx.x, t = threadIdx.x;
    int nlo = b << BSH;
    int cn = N - nlo; if (cn > BSZ) cn = BSZ;
    int e0 = eoff[b], ec = bcount[b], cb = boff[b];
    sdeg[t] = (t < cn) ? 1 : 0;
    __syncthreads();
    for (int i = t; i < ec; i += 512)
        atomicAdd(&sdeg[ebuf[e0 + i] & (BSZ - 1)], 1);
    __syncthreads();
    int v = sdeg[t];
    sscan[t] = v;
    __syncthreads();
#pragma unroll
    for (int off = 1; off < BSZ; off <<= 1) {
        int u = (t >= off) ? sscan[t - off] : 0;
        __syncthreads();
        sscan[t] += u;
        __syncthreads();
    }
    int excl = sscan[t] - v;
    if (t < cn) {
        rowptr[nlo + t] = cb + excl;
        csr[cb + excl] = nlo + t;
        sdeg[t] = excl + 1;
    }
    __syncthreads();
    for (int i = t; i < ec; i += 512) {
        int rec = ebuf[e0 + i];
        int p = atomicAdd(&sdeg[rec & (BSZ - 1)], 1);
        csr[cb + p] = rec >> BSH;
    }
}

// ---------------- GEMM: H = X @ W (+bias), optional ss/sd, optional bf16 H ----

template <int K, int OUTW, bool SS, bool HB>
__global__ __launch_bounds__(256) void k_gemm(const float* __restrict__ X,
                                              const float* __restrict__ W,
                                              const float* __restrict__ a_s,
                                              const float* __restrict__ a_d,
                                              const float* __restrict__ bias,
                                              void* __restrict__ Hout,
                                              float* __restrict__ ss,
                                              float* __restrict__ sd, int N) {
    constexpr int CH = 16;
    constexpr int XS = 132;
    __shared__ __align__(16) float ws[K * 64];
    __shared__ __align__(16) float xs[CH * XS];

    if (OUTW == 64) {
        for (int i = threadIdx.x * 4; i < K * 64; i += 1024)
            *(float4*)&ws[i] = *(const float4*)&W[i];
    } else {
        for (int i = threadIdx.x; i < K * 64; i += 256) {
            int k = i >> 6, o = i & 63;
            ws[i] = (o < OUTW) ? W[k * OUTW + o] : 0.f;
        }
    }

    const int lane = threadIdx.x & 63;
    const int w    = threadIdx.x >> 6;
    const int rg   = lane >> 3;
    const int og   = lane & 7;
    const int rowbase = blockIdx.x * 128;
    const int rr   = w * 32 + rg * 4;
    const int r0   = rowbase + rr;

    float acc[4][8];
#pragma unroll
    for (int i = 0; i < 4; ++i)
#pragma unroll
        for (int j = 0; j < 8; ++j) acc[i][j] = 0.f;

    for (int kc = 0; kc < K; kc += CH) {
        __syncthreads();
#pragma unroll
        for (int it = 0; it < 2; ++it) {
            int idx = it * 256 + threadIdx.x;
            int row = idx >> 2;
            int q   = idx & 3;
            int grow = rowbase + row; grow = grow < N ? grow : N - 1;
            float4 v = *(const float4*)&X[(size_t)grow * K + kc + q * 4];
            xs[(q * 4 + 0) * XS + row] = v.x;
            xs[(q * 4 + 1) * XS + row] = v.y;
            xs[(q * 4 + 2) * XS + row] = v.z;
            xs[(q * 4 + 3) * XS + row] = v.w;
        }
        __syncthreads();
#pragma unroll
        for (int k = 0; k < CH; ++k) {
            const float4 a  = *(const float4*)&xs[k * XS + rr];
            const float4 b0 = *(const float4*)&ws[(kc + k) * 64 + og * 8];
            const float4 b1 = *(const float4*)&ws[(kc + k) * 64 + og * 8 + 4];
            const float av[4]  = {a.x, a.y, a.z, a.w};
            const float bv8[8] = {b0.x, b0.y, b0.z, b0.w, b1.x, b1.y, b1.z, b1.w};
#pragma unroll
            for (int i = 0; i < 4; ++i)
#pragma unroll
                for (int j = 0; j < 8; ++j)
                    acc[i][j] = fmaf(av[i], bv8[j], acc[i][j]);
        }
    }

    if (SS) {
        float asv[8], adv[8];
        *(float4*)&asv[0] = *(const float4*)&a_s[og * 8];
        *(float4*)&asv[4] = *(const float4*)&a_s[og * 8 + 4];
        *(float4*)&adv[0] = *(const float4*)&a_d[og * 8];
        *(float4*)&adv[4] = *(const float4*)&a_d[og * 8 + 4];
#pragma unroll
        for (int i = 0; i < 4; ++i) {
            float s = 0.f, d = 0.f;
#pragma unroll
            for (int j = 0; j < 8; ++j) {
                s = fmaf(acc[i][j], asv[j], s);
                d = fmaf(acc[i][j], adv[j], d);
            }
#pragma unroll
            for (int o = 1; o <= 4; o <<= 1) {
                s += __shfl_xor(s, o, 64);
                d += __shfl_xor(d, o, 64);
            }
            if (og == 0 && r0 + i < N) { ss[r0 + i] = s; sd[r0 + i] = d; }
        }
    }

#pragma unroll
    for (int i = 0; i < 4; ++i) {
        int r = r0 + i;
        if (r >= N) continue;
        if (HB) {
            unsigned int* hb = (unsigned int*)Hout;
            uint4 u;
            u.x = (f2bf(acc[i][1]) << 16) | f2bf(acc[i][0]);
            u.y = (f2bf(acc[i][3]) << 16) | f2bf(acc[i][2]);
            u.z = (f2bf(acc[i][5]) << 16) | f2bf(acc[i][4]);
            u.w = (f2bf(acc[i][7]) << 16) | f2bf(acc[i][6]);
            *(uint4*)&hb[(size_t)r * 32 + og * 4] = u;
        } else if (OUTW == 64) {
            float* H = (float*)Hout;
            float4 o0 = make_float4(acc[i][0], acc[i][1], acc[i][2], acc[i][3]);
            float4 o1 = make_float4(acc[i][4], acc[i][5], acc[i][6], acc[i][7]);
            *(float4*)&H[(size_t)r * 64 + og * 8]     = o0;
            *(float4*)&H[(size_t)r * 64 + og * 8 + 4] = o1;
        } else {
            float* H = (float*)Hout;
#pragma unroll
            for (int j = 0; j < 8; ++j) {
                int o = og * 8 + j;
                if (o < OUTW) H[(size_t)r * OUTW + o] = acc[i][j] + bias[o];
            }
        }
    }
}

// ---------------- Aggregation: z[n] = elu( sum_j alpha_j h[src_j] + b ) ------
// half-wave (32 lanes) per node, 8 nodes/block. Softmax without max-subtraction
// (scores bounded ~|10| << 88, shift-invariant). One fused score+exp+sum pass,
// then gather: lane p holds packed bf16 features 2p,2p+1 of the accumulator.

__global__ __launch_bounds__(256) void k_agg(const int* __restrict__ rowptr, const int* __restrict__ csr,
                                             const float* __restrict__ ss, const float* __restrict__ sd,
                                             const unsigned int* __restrict__ hb, const float* __restrict__ bias,
                                             float* __restrict__ z, int N) {
    __shared__ float2 ps[8 * CAP];
    const int tid = threadIdx.x;
    const int hw  = tid >> 5;          // half-wave 0..7 (node slot)
    const int p   = tid & 31;
    const int n   = blockIdx.x * 8 + hw;
    const bool valid = n < N;
    float2* myps = ps + hw * CAP;

    int ro = 0, deg = 0;
    float sdn = 0.f;
    if (valid) {
        ro  = rowptr[n];
        deg = rowptr[n + 1] - ro;
        sdn = sd[n];
    }

    if (deg <= CAP) {
        // fused score + exp + partial sum
        float sum = 0.f;
        for (int j = p; j < deg; j += 32) {
            int s = csr[ro + j];
            float e = ss[s] + sdn;
            e = fmaxf(e, NEG_SLOPE * e);
            float pe = __expf(e);
            myps[j] = make_float2(pe, __int_as_float(s));
            sum += pe;
        }
        sum = hred_sum(sum);
        float inv = 1.f / (sum + 1e-16f);

        // weighted gather, 4 edges in flight per half-wave
        float ax = 0.f, ay = 0.f, bx = 0.f, by = 0.f, cx = 0.f, cy = 0.f, dx = 0.f, dy = 0.f;
        int j = 0;
        for (; j + 3 < deg; j += 4) {
            float2 e0 = myps[j], e1 = myps[j + 1], e2 = myps[j + 2], e3 = myps[j + 3];
            unsigned int u0 = hb[(size_t)__float_as_int(e0.y) * 32 + p];
            unsigned int u1 = hb[(size_t)__float_as_int(e1.y) * 32 + p];
            unsigned int u2 = hb[(size_t)__float_as_int(e2.y) * 32 + p];
            unsigned int u3 = hb[(size_t)__float_as_int(e3.y) * 32 + p];
            ax = fmaf(bflo(u0), e0.x, ax); ay = fmaf(bfhi(u0), e0.x, ay);
            bx = fmaf(bflo(u1), e1.x, bx); by = fmaf(bfhi(u1), e1.x, by);
            cx = fmaf(bflo(u2), e2.x, cx); cy = fmaf(bfhi(u2), e2.x, cy);
            dx = fmaf(bflo(u3), e3.x, dx); dy = fmaf(bfhi(u3), e3.x, dy);
        }
        for (; j < deg; ++j) {
            float2 e0 = myps[j];
            unsigned int u0 = hb[(size_t)__float_as_int(e0.y) * 32 + p];
            ax = fmaf(bflo(u0), e0.x, ax); ay = fmaf(bfhi(u0), e0.x, ay);
        }
        float fx = (ax + bx) + (cx + dx);
        float fy = (ay + by) + (cy + dy);
        if (valid) {
            float2 ob = *(const float2*)&bias[p * 2];
            float ox = fmaf(fx, inv, ob.x);
            float oy = fmaf(fy, inv, ob.y);
            ox = (ox > 0.f) ? ox : __expf(ox) - 1.f;
            oy = (oy > 0.f) ? oy : __expf(oy) - 1.f;
            *(float2*)&z[(size_t)n * 64 + p * 2] = make_float2(ox, oy);
        }
    } else {
        // recompute fallback (deg > CAP): statistically never taken
        float sum = 0.f;
        for (int j = p; j < deg; j += 32) {
            int s = csr[ro + j];
            float e = ss[s] + sdn;
            e = fmaxf(e, NEG_SLOPE * e);
            sum += __expf(e);
        }
        sum = hred_sum(sum);
        float inv = 1.f / (sum + 1e-16f);
        float fx = 0.f, fy = 0.f;
        for (int j = 0; j < deg; ++j) {
            int s = csr[ro + j];
            float e = ss[s] + sdn;
            e = fmaxf(e, NEG_SLOPE * e);
            float pe = __expf(e);
            unsigned int u = hb[(size_t)s * 32 + p];
            fx = fmaf(bflo(u), pe, fx); fy = fmaf(bfhi(u), pe, fy);
        }
        float2 ob = *(const float2*)&bias[p * 2];
        float ox = fmaf(fx, inv, ob.x);
        float oy = fmaf(fy, inv, ob.y);
        ox = (ox > 0.f) ? ox : __expf(ox) - 1.f;
        oy = (oy > 0.f) ? oy : __expf(oy) - 1.f;
        *(float2*)&z[(size_t)n * 64 + p * 2] = make_float2(ox, oy);
    }
}

// ---------------- launch ----------------

extern "C" void kernel_launch(void* const* d_in, const int* in_sizes, int n_in,
                              void* d_out, int out_size, void* d_ws, size_t ws_size,
                              hipStream_t stream) {
    const float* x   = (const float*)d_in[0];
    const int*   ei  = (const int*)d_in[1];
    const float* W0  = (const float*)d_in[2];
    const float* as0 = (const float*)d_in[3];
    const float* ad0 = (const float*)d_in[4];
    const float* b0  = (const float*)d_in[5];
    const float* W1  = (const float*)d_in[6];
    const float* as1 = (const float*)d_in[7];
    const float* ad1 = (const float*)d_in[8];
    const float* b1  = (const float*)d_in[9];
    const float* Wl  = (const float*)d_in[10];
    const float* bl  = (const float*)d_in[11];
    float* out = (float*)d_out;

    int N = in_sizes[0] / 128;
    int E = in_sizes[1] / 2;
    const int* srcp = ei;
    const int* dstp = ei + E;
    int nbuck = (N + BSZ - 1) >> BSH;

    char* wp = (char*)d_ws;
    auto alloc = [&](size_t bytes) { void* p = (void*)wp; wp += (bytes + 255) & ~(size_t)255; return p; };
    unsigned int* hb = (unsigned int*)alloc((size_t)N * 32 * 4);   // bf16-packed h
    float* z       = (float*)alloc((size_t)N * 64 * 4);
    float* ssb     = (float*)alloc((size_t)N * 4);
    float* sdb     = (float*)alloc((size_t)N * 4);
    int*   rowptr  = (int*)alloc((size_t)(N + 1) * 4);
    int*   csr     = (int*)alloc((size_t)(E + N) * 4);
    int*   ebuf    = (int*)alloc((size_t)E * 4);
    int*   bcount  = (int*)alloc(256 * 4);
    int*   eoff    = (int*)alloc(256 * 4);
    int*   boff    = (int*)alloc(256 * 4);
    int*   bcursor = (int*)alloc(256 * 4);

    // CSR build
    k_zero<<<1, 256, 0, stream>>>(bcount, 256);
    k_hist<<<256, 256, 0, stream>>>(dstp, bcount, E);
    k_bscan<<<1, 256, 0, stream>>>(bcount, eoff, boff, bcursor, rowptr, nbuck, N, E);
    k_scatter<<<(E + CHUNK - 1) / CHUNK, 256, 0, stream>>>(srcp, dstp, bcursor, ebuf, E);
    k_build<<<nbuck, 512, 0, stream>>>(eoff, boff, bcount, ebuf, rowptr, csr, N);

    int gb = (N + 127) / 128;
    // layer 0
    k_gemm<128, 64, true, true><<<gb, 256, 0, stream>>>(x, W0, as0, ad0, nullptr, hb, ssb, sdb, N);
    k_agg<<<(N + 7) / 8, 256, 0, stream>>>(rowptr, csr, ssb, sdb, hb, b0, z, N);
    // layer 1
    k_gemm<64, 64, true, true><<<gb, 256, 0, stream>>>(z, W1, as1, ad1, nullptr, hb, ssb, sdb, N);
    k_agg<<<(N + 7) / 8, 256, 0, stream>>>(rowptr, csr, ssb, sdb, hb, b1, z, N);
    // classifier
    k_gemm<64, 40, false, false><<<gb, 256, 0, stream>>>(z, Wl, nullptr, nullptr, bl, out, nullptr, nullptr, N);
}